// Round 7
// baseline (412.855 us; speedup 1.0000x reference)
//
#include <hip/hip_runtime.h>

// LocalGraphTransformerEncoder on MI355X (gfx950). Round 7.
// R6 post-mortem: launch overhead ~1.5us/dispatch (not the bottleneck);
// time is inside the ~20-40us kernels. simz's per-edge rowsum atomics
// (256-way contention on star rows) + esim global round-trip + double
// feature compute were the suspects.
// R7: simz+accum merged into k_edge (chunk-local sims in LDS, one rowsum
// atomic per chunk per head, unnormalized t/vs accumulation); epi GEMM
// normalizes by 1/S during A-staging and residual add (AMODE=4).

#define MAXE  16384
#define NONX  22080
#define BF16_TOTAL 1441792

typedef __attribute__((ext_vector_type(8))) short bf16x8;
typedef __attribute__((ext_vector_type(4))) float f32x4;

struct PtrPack { const void* p[23]; };

__device__ __forceinline__ float bf2f(unsigned short s) {
  return __uint_as_float(((unsigned)s) << 16);
}
__device__ __forceinline__ unsigned short f2bf(float f) {
  unsigned u = __float_as_uint(f);
  u += 0x7fffu + ((u >> 16) & 1u);
  return (unsigned short)(u >> 16);
}
__device__ __forceinline__ float gelu_f(float x) {
  return 0.5f * x * (1.0f + erff(x * 0.70710678118654752440f));
}
__device__ __forceinline__ float wave_red_sum(float v) {
#pragma unroll
  for (int o = 32; o > 0; o >>= 1) v += __shfl_xor(v, o);
  return v;
}

__device__ __forceinline__ void edge_feats(int i, int j, float cxi, float cyi,
                                           float cxj, float cyj, float lsd, float* e) {
  float dx = cxj - cxi, dy = cyj - cyi;
  float dist = sqrtf(dx * dx + dy * dy + 1e-8f);
  e[0] = dx; e[1] = dy; e[2] = dist; e[3] = dist / lsd;
  bool qic = (i == 0), kic = (j == 0), eye = (i == j);
  e[4] = qic ? 1.f : 0.f;
  e[5] = kic ? 1.f : 0.f;
  e[6] = eye ? 1.f : 0.f;
  e[7] = (!qic && !kic && !eye) ? 1.f : 0.f;
  int hi = (i == 0) ? 0 : ((i < 128) ? 1 : 2);
  int hj = (j == 0) ? 0 : ((j < 128) ? 1 : 2);
  e[8] = (hi == hj) ? 1.f : 0.f;
  int hd = hj - hi;
  e[9] = (float)(hd < 0 ? -hd : hd);
}

// ---------- convert: fp32 smalls + bf16 weights + valid + zero rowsum/tb/vs ----------
__global__ __launch_bounds__(256) void k_convert(PtrPack pp, float* __restrict__ blobF,
                                                 unsigned short* __restrict__ blobB,
                                                 int* __restrict__ valid,
                                                 float* __restrict__ rowsum,
                                                 float* __restrict__ tbvs,
                                                 int* __restrict__ gctr) {
  bool isf32 = (*(const unsigned*)pp.p[15] == 0x3F800000u);
  int t = threadIdx.x;
  if (blockIdx.x == 0 && t == 0) *gctr = 0;
  if (blockIdx.x < 1024) {
    if (blockIdx.x < 32) rowsum[blockIdx.x * 256 + t] = 0.f;
    int r = blockIdx.x;
    int idx = r * 256 + t;
    float v = isf32 ? ((const float*)pp.p[0])[idx]
                    : bf2f(((const unsigned short*)pp.p[0])[idx]);
    blobF[idx] = v;
    __shared__ float s[4];
    float a = wave_red_sum(fabsf(v));
    if ((t & 63) == 0) s[t >> 6] = a;
    __syncthreads();
    if (t == 0) valid[r] = ((s[0] + s[1] + s[2] + s[3]) > 0.0f) || ((r & 255) == 0);
  } else {
    // zero tb (4MB) + vs (1MB) for layer 0
    for (int z = (blockIdx.x - 1024) * 256 + t; z < 1310720; z += 262144)
      tbvs[z] = 0.f;
    const int fst[16] = {0,2048,7680,8192,10240,10304,15936,16448,16960,17472,17984,18496,19008,19520,21568,22080};
    const int fsz[15] = {2048,5632,512,2048,8,5632,512,512,512,512,512,512,512,2048,512};
    const int fin[15] = {1,5,6,7,8,9,10,12,14,15,16,17,18,20,22};
    const int bst[8]  = {0,131072,262144,393216,524288,655360,1179648,1441792};
    const int bin[7]  = {2,3,4,13,11,19,21};
    for (int idx = (blockIdx.x - 1024) * 256 + t; idx < NONX + BF16_TOTAL; idx += 1024 * 256) {
      if (idx < NONX) {
        int s = 0;
        while (s < 14 && idx >= fst[s + 1]) ++s;
        int e = idx - fst[s];
        float v = 0.f;
        if (e < fsz[s]) v = isf32 ? ((const float*)pp.p[fin[s]])[e]
                                  : bf2f(((const unsigned short*)pp.p[fin[s]])[e]);
        blobF[262144 + idx] = v;
      } else {
        int bi = idx - NONX;
        int s = 0;
        while (s < 6 && bi >= bst[s + 1]) ++s;
        int e = bi - bst[s];
        blobB[bi] = isf32 ? f2bf(((const float*)pp.p[bin[s]])[e])
                          : ((const unsigned short*)pp.p[bin[s]])[e];
      }
    }
  }
}

// ---------- kNN ----------
__global__ __launch_bounds__(256) void k_knn(const float* __restrict__ cf,
                                             const int* __restrict__ valid,
                                             int* __restrict__ knn) {
  int blk = blockIdx.x;
  int b = blk >> 6;
  int w = threadIdx.x >> 6, lane = threadIdx.x & 63;
  int i = (blk & 63) * 4 + w;
  const float2* cc = (const float2*)(cf + b * 512);
  float2 ci = cc[i];
  bool vi = (valid[b * 256 + i] != 0) && (i != 0);
  unsigned long long key[4];
#pragma unroll
  for (int k = 0; k < 4; ++k) {
    int j = lane + 64 * k;
    bool ok = vi && (j != 0) && (j != i) && (valid[b * 256 + j] != 0);
    unsigned long long kk = ~0ull;
    if (ok) {
      float2 cj = cc[j];
      float dx = ci.x - cj.x, dy = ci.y - cj.y;
      float dd = sqrtf(dx * dx + dy * dy);
      kk = (((unsigned long long)__float_as_uint(dd)) << 32) | (unsigned)j;
    }
    key[k] = kk;
  }
  int out[3];
#pragma unroll
  for (int rnd = 0; rnd < 3; ++rnd) {
    unsigned long long m = key[0];
    if (key[1] < m) m = key[1];
    if (key[2] < m) m = key[2];
    if (key[3] < m) m = key[3];
#pragma unroll
    for (int o = 32; o > 0; o >>= 1) {
      unsigned long long om = __shfl_xor(m, o);
      if (om < m) m = om;
    }
    out[rnd] = (m != ~0ull) ? (int)(m & 0xFFFFFFFFull) : -1;
#pragma unroll
    for (int k = 0; k < 4; ++k)
      if (key[k] == m) key[k] = ~0ull;
  }
  if (lane == 0) {
    knn[(b * 256 + i) * 3 + 0] = out[0];
    knn[(b * 256 + i) * 3 + 1] = out[1];
    knn[(b * 256 + i) * 3 + 2] = out[2];
  }
}

// ---------- CSR build (shuffle scan) ----------
__global__ __launch_bounds__(256) void k_csr(const float* __restrict__ cf,
                                             const int* __restrict__ valid,
                                             const int* __restrict__ knn,
                                             float* __restrict__ lsbuf,
                                             int* __restrict__ deg, int* __restrict__ rowptr,
                                             int* __restrict__ colsb,
                                             int* __restrict__ gctr) {
  int b = blockIdx.x, t = threadIdx.x;
  __shared__ unsigned adjw[256][8];
  __shared__ float sred[8];
  __shared__ int wsum[4];
  __shared__ int sbase;

  int r = b * 256 + t;
  float cx = cf[r * 2 + 0], cy = cf[r * 2 + 1];
  int lv = valid[r];
#pragma unroll
  for (int w = 0; w < 8; ++w) adjw[t][w] = 0u;
  __syncthreads();

  atomicOr(&adjw[t][t >> 5], 1u << (t & 31));
  if (t >= 1 && lv) {
    atomicOr(&adjw[0][t >> 5], 1u << (t & 31));
    atomicOr(&adjw[t][0], 1u);
  }
#pragma unroll
  for (int s = 0; s < 3; ++s) {
    int j = knn[r * 3 + s];
    if (j >= 0) {
      atomicOr(&adjw[t][j >> 5], 1u << (j & 31));
      atomicOr(&adjw[j][t >> 5], 1u << (t & 31));
    }
  }
  float cdist = sqrtf(cx * cx + cy * cy + 1e-8f);
  int nvm = (t >= 1) && lv;
  float rs = wave_red_sum(nvm ? cdist : 0.0f);
  float rc = wave_red_sum(nvm ? 1.0f : 0.0f);
  if ((t & 63) == 0) { sred[t >> 6] = rs; sred[4 + (t >> 6)] = rc; }
  __syncthreads();

  if (t == 0) {
    float totd = sred[0] + sred[1] + sred[2] + sred[3];
    float totc = sred[4] + sred[5] + sred[6] + sred[7];
    float ls = totd / fmaxf(totc, 1.0f);
    ls = (ls > 0.0f) ? ls : 1.0f;
    lsbuf[b] = fmaxf(ls, 1e-6f);
  }

  int dg = 0;
#pragma unroll
  for (int w = 0; w < 8; ++w) dg += __popc(adjw[t][w]);

  int lane = t & 63, wv = t >> 6;
  int x = dg;
#pragma unroll
  for (int off = 1; off < 64; off <<= 1) {
    int y = __shfl_up(x, off);
    if (lane >= off) x += y;
  }
  if (lane == 63) wsum[wv] = x;
  __syncthreads();
  if (t == 0) sbase = atomicAdd(gctr, wsum[0] + wsum[1] + wsum[2] + wsum[3]);
  __syncthreads();
  int woff = 0;
#pragma unroll
  for (int k2 = 0; k2 < 4; ++k2) woff += (k2 < wv) ? wsum[k2] : 0;
  int off0 = sbase + woff + x - dg;

  rowptr[r] = off0;
  deg[r] = dg;
  int o = off0;
#pragma unroll
  for (int w = 0; w < 8; ++w) {
    unsigned bits = adjw[t][w];
    while (bits) {
      int bp = __ffs(bits) - 1;
      colsb[o] = w * 32 + bp;
      ++o;
      bits &= bits - 1;
    }
  }
}

// ---------- bf16 MFMA GEMM body ----------
// AMODE: 0=bf16 A | 1=gated fp32 (gate +512, lda=1024) | 2=plain fp32
//        3=LN-fused fp32 | 4=fp32 scaled by 1/rowsum[(row)*4+rsh] (resid scaled too)
// OMODE: 0=fp32 | 1=probe bf16/fp32 | 2=bf16
template <int AMODE, int OMODE>
__device__ __forceinline__ void mfma_body(const void* Aptr, int lda,
                                          const unsigned short* __restrict__ B, int ldb, int n0B,
                                          const float* __restrict__ bias,
                                          const float* resid,
                                          void* C, int ldc, int n0C,
                                          int m0, int K, bool obf,
                                          const float* __restrict__ lnG,
                                          const float* __restrict__ lnB,
                                          const float* __restrict__ rs4, int rsh) {
  __shared__ short As[64][40];
  __shared__ short Bs[64][40];
  __shared__ float sG[256], sB2[256], sMean[64], sRstd[64];
  __shared__ float sSc[64];
  int t = threadIdx.x, lane = t & 63, w = t >> 6;

  if (AMODE == 3) {
    sG[t] = lnG[t]; sB2[t] = lnB[t];
    int row = t >> 2, qq = t & 3;
    const float* xr = (const float*)Aptr + (size_t)(m0 + row) * lda + qq * 64;
    float s = 0.f, ss = 0.f;
#pragma unroll
    for (int ii = 0; ii < 16; ++ii) {
      float4 v4 = *(const float4*)(xr + ii * 4);
      s += v4.x + v4.y + v4.z + v4.w;
      ss += v4.x * v4.x + v4.y * v4.y + v4.z * v4.z + v4.w * v4.w;
    }
    s += __shfl_xor(s, 1); s += __shfl_xor(s, 2);
    ss += __shfl_xor(ss, 1); ss += __shfl_xor(ss, 2);
    if (qq == 0) {
      float m = s * (1.f / 256.f);
      float var = ss * (1.f / 256.f) - m * m;
      sMean[row] = m;
      sRstd[row] = 1.f / sqrtf(var + 1e-5f);
    }
    __syncthreads();
  }
  if (AMODE == 4) {
    if (t < 64) sSc[t] = 1.0f / rs4[(m0 + t) * 4 + rsh];
    __syncthreads();
  }

  f32x4 acc[4];
#pragma unroll
  for (int nt = 0; nt < 4; ++nt)
#pragma unroll
    for (int e = 0; e < 4; ++e) acc[nt][e] = 0.0f;

  int am = t >> 2, ak = (t & 3) * 8;
  int bk = t >> 3, bn = (t & 7) * 8;

  for (int k0 = 0; k0 < K; k0 += 32) {
    if (AMODE == 0) {
      const unsigned short* ap = (const unsigned short*)Aptr + (size_t)(m0 + am) * lda + k0 + ak;
      bf16x8 av = *(const bf16x8*)ap;
      *(bf16x8*)&As[am][ak] = av;
    } else if (AMODE == 1) {
      const float* ap = (const float*)Aptr + (size_t)(m0 + am) * lda + k0 + ak;
      float4 a0 = *(const float4*)ap;
      float4 a1 = *(const float4*)(ap + 4);
      float4 g0 = *(const float4*)(ap + 512);
      float4 g1 = *(const float4*)(ap + 516);
      short tmp[8];
      tmp[0] = (short)f2bf(a0.x * gelu_f(g0.x));
      tmp[1] = (short)f2bf(a0.y * gelu_f(g0.y));
      tmp[2] = (short)f2bf(a0.z * gelu_f(g0.z));
      tmp[3] = (short)f2bf(a0.w * gelu_f(g0.w));
      tmp[4] = (short)f2bf(a1.x * gelu_f(g1.x));
      tmp[5] = (short)f2bf(a1.y * gelu_f(g1.y));
      tmp[6] = (short)f2bf(a1.z * gelu_f(g1.z));
      tmp[7] = (short)f2bf(a1.w * gelu_f(g1.w));
      *(bf16x8*)&As[am][ak] = *(bf16x8*)tmp;
    } else if (AMODE == 2 || AMODE == 4) {
      const float* ap = (const float*)Aptr + (size_t)(m0 + am) * lda + k0 + ak;
      float4 a0 = *(const float4*)ap;
      float4 a1 = *(const float4*)(ap + 4);
      float sc = (AMODE == 4) ? sSc[am] : 1.0f;
      short tmp[8];
      tmp[0] = (short)f2bf(a0.x * sc); tmp[1] = (short)f2bf(a0.y * sc);
      tmp[2] = (short)f2bf(a0.z * sc); tmp[3] = (short)f2bf(a0.w * sc);
      tmp[4] = (short)f2bf(a1.x * sc); tmp[5] = (short)f2bf(a1.y * sc);
      tmp[6] = (short)f2bf(a1.z * sc); tmp[7] = (short)f2bf(a1.w * sc);
      *(bf16x8*)&As[am][ak] = *(bf16x8*)tmp;
    } else {
      const float* ap = (const float*)Aptr + (size_t)(m0 + am) * lda + k0 + ak;
      float4 a0 = *(const float4*)ap;
      float4 a1 = *(const float4*)(ap + 4);
      float mm = sMean[am], rr = sRstd[am];
      short tmp[8];
      int kb = k0 + ak;
      tmp[0] = (short)f2bf((a0.x - mm) * rr * sG[kb + 0] + sB2[kb + 0]);
      tmp[1] = (short)f2bf((a0.y - mm) * rr * sG[kb + 1] + sB2[kb + 1]);
      tmp[2] = (short)f2bf((a0.z - mm) * rr * sG[kb + 2] + sB2[kb + 2]);
      tmp[3] = (short)f2bf((a0.w - mm) * rr * sG[kb + 3] + sB2[kb + 3]);
      tmp[4] = (short)f2bf((a1.x - mm) * rr * sG[kb + 4] + sB2[kb + 4]);
      tmp[5] = (short)f2bf((a1.y - mm) * rr * sG[kb + 5] + sB2[kb + 5]);
      tmp[6] = (short)f2bf((a1.z - mm) * rr * sG[kb + 6] + sB2[kb + 6]);
      tmp[7] = (short)f2bf((a1.w - mm) * rr * sG[kb + 7] + sB2[kb + 7]);
      *(bf16x8*)&As[am][ak] = *(bf16x8*)tmp;
    }
    {
      const unsigned short* bp = B + (size_t)(k0 + bk) * ldb + n0B + bn;
      bf16x8 bv = *(const bf16x8*)bp;
      Bs[bn + 0][bk] = bv[0]; Bs[bn + 1][bk] = bv[1];
      Bs[bn + 2][bk] = bv[2]; Bs[bn + 3][bk] = bv[3];
      Bs[bn + 4][bk] = bv[4]; Bs[bn + 5][bk] = bv[5];
      Bs[bn + 6][bk] = bv[6]; Bs[bn + 7][bk] = bv[7];
    }
    __syncthreads();
    int q = lane >> 4;
    bf16x8 af = *(const bf16x8*)&As[w * 16 + (lane & 15)][q * 8];
#pragma unroll
    for (int nt = 0; nt < 4; ++nt) {
      bf16x8 bf = *(const bf16x8*)&Bs[nt * 16 + (lane & 15)][q * 8];
      acc[nt] = __builtin_amdgcn_mfma_f32_16x16x32_bf16(af, bf, acc[nt], 0, 0, 0);
    }
    __syncthreads();
  }

  int q = lane >> 4;
#pragma unroll
  for (int nt = 0; nt < 4; ++nt) {
    int col = n0C + nt * 16 + (lane & 15);
    float bv = bias ? bias[n0B + nt * 16 + (lane & 15)] : 0.0f;
#pragma unroll
    for (int rr = 0; rr < 4; ++rr) {
      int row = m0 + w * 16 + q * 4 + rr;
      float v = acc[nt][rr] + bv;
      if (resid) {
        float rv = resid[(size_t)row * ldc + col];
        v += (AMODE == 4) ? rv * sSc[row - m0] : rv;
      }
      if (OMODE == 2 || (OMODE == 1 && obf)) {
        ((unsigned short*)C)[(size_t)row * ldc + col] = f2bf(v);
      } else {
        ((float*)C)[(size_t)row * ldc + col] = v;
      }
    }
  }
}

template <int AMODE, int OMODE>
__global__ __launch_bounds__(256) void k_mfma(const void* A, int lda, int aYoffBytes,
                                              const unsigned short* B, int ldb,
                                              const float* bias, const float* resid,
                                              void* C, int ldc, int K,
                                              const unsigned* probe,
                                              const float* lnG, const float* lnB,
                                              const float* rs4) {
  bool obf = (OMODE == 1) && probe && (*probe != 0x3F800000u);
  int n0 = blockIdx.y * 64;
  const void* Ap = (const char*)A + (size_t)aYoffBytes * blockIdx.y;
  mfma_body<AMODE, OMODE>(Ap, lda, B, ldb, n0, bias, resid, C, ldc, n0,
                          blockIdx.x * 64, K, obf, lnG, lnB, rs4, blockIdx.y);
}

__global__ __launch_bounds__(256) void k_mfma_qkv(const float* X,
                                                  const float* lnG, const float* lnB,
                                                  const unsigned short* WqL, float* qkv) {
  int sel = blockIdx.y >> 2;
  const unsigned short* B = WqL + sel * 131072;
  int n0B = (blockIdx.y & 3) * 64;
  int n0C = blockIdx.y * 64;
  mfma_body<3, 0>(X, 256, B, 256, n0B, nullptr, nullptr, qkv, 768, n0C,
                  blockIdx.x * 64, 256, false, lnG, lnB, nullptr, 0);
}

// ---------- fused edge kernel: block per (row, 32-edge chunk) ----------
// phase A: exp-sims into LDS (wave per edge); chunk sums -> 4 rowsum atomics;
// phase B: unnormalized t~/v~ accumulation (atomics). Normalization in epi.
__global__ __launch_bounds__(256, 4) void k_edge(const float* __restrict__ cf,
                                                 const float* __restrict__ qkv,
                                                 const int* __restrict__ rowptr,
                                                 const int* __restrict__ deg,
                                                 const int* __restrict__ colsb,
                                                 const float* __restrict__ lsbuf,
                                                 const float* __restrict__ ebW1,
                                                 const float* __restrict__ ebB1,
                                                 const float* __restrict__ ebW2,
                                                 const float* __restrict__ ebB2,
                                                 const float* __restrict__ evW1,
                                                 const float* __restrict__ evB1,
                                                 float* __restrict__ rowsum,
                                                 float* __restrict__ tb,
                                                 float* __restrict__ vs) {
  int rc = blockIdx.x;
  int r = rc >> 3, ch = rc & 7;
  int d = deg[r];
  int e0 = ch * 32;
  if (e0 >= d) return;
  int n = min(32, d - e0);
  int base = rowptr[r] + e0;
  int b = r >> 8, i = r & 255;
  int u = threadIdx.x, lane = u & 63, w = u >> 6;

  __shared__ float sq[256];
  __shared__ int scols[32];
  __shared__ float sef[32][10];
  __shared__ float sexp[32][4];
  sq[u] = qkv[(size_t)r * 768 + u];
  if (u < n) {
    int j = colsb[base + u];
    scols[u] = j;
    float ls = lsbuf[b];
    const float2* cc = (const float2*)cf;
    float2 ci = cc[b * 256 + i], cj = cc[b * 256 + j];
    float ef[10];
    edge_feats(i, j, ci.x, ci.y, cj.x, cj.y, ls, ef);
#pragma unroll
    for (int f = 0; f < 10; ++f) sef[u][f] = ef[f];
  }
  __syncthreads();

  // phase A: wave per edge
  {
    float W1r[4][10], B1r[4], W2r[4][4];
#pragma unroll
    for (int kk = 0; kk < 4; ++kk) {
      int c = kk * 64 + lane;
      B1r[kk] = ebB1[c];
#pragma unroll
      for (int f = 0; f < 10; ++f) W1r[kk][f] = ebW1[f * 256 + c];
      float4 w2 = *(const float4*)(ebW2 + c * 4);
      W2r[kk][0] = w2.x; W2r[kk][1] = w2.y; W2r[kk][2] = w2.z; W2r[kk][3] = w2.w;
    }
    float b20 = ebB2[0], b21 = ebB2[1], b22 = ebB2[2], b23 = ebB2[3];
    for (int e = w; e < n; e += 4) {
      int j = scols[e];
      float red[8];
#pragma unroll
      for (int z = 0; z < 8; ++z) red[z] = 0.0f;
#pragma unroll
      for (int kk = 0; kk < 4; ++kk) {
        int c = kk * 64 + lane;
        float h1 = B1r[kk];
#pragma unroll
        for (int f = 0; f < 10; ++f) h1 += sef[e][f] * W1r[kk][f];
        float g1 = gelu_f(h1);
        red[4] += g1 * W2r[kk][0];
        red[5] += g1 * W2r[kk][1];
        red[6] += g1 * W2r[kk][2];
        red[7] += g1 * W2r[kk][3];
        red[kk] = sq[c] * qkv[((size_t)(b * 256 + j)) * 768 + 256 + c];
      }
#pragma unroll
      for (int z = 0; z < 8; ++z) {
#pragma unroll
        for (int o = 32; o > 0; o >>= 1) red[z] += __shfl_xor(red[z], o);
      }
      if (lane == 0) {
        sexp[e][0] = expf(red[0] * 0.125f + red[4] + b20);
        sexp[e][1] = expf(red[1] * 0.125f + red[5] + b21);
        sexp[e][2] = expf(red[2] * 0.125f + red[6] + b22);
        sexp[e][3] = expf(red[3] * 0.125f + red[7] + b23);
      }
    }
  }
  __syncthreads();

  // chunk sums -> one rowsum atomic per head
  if (u < 4) {
    float s = 0.f;
    for (int e = 0; e < n; ++e) s += sexp[e][u];
    atomicAdd(&rowsum[r * 4 + u], s);
  }

  // phase B: channel-per-thread accumulation (unnormalized)
  int h = u >> 6;
  float evb = evB1[u];
  float w1r[10];
#pragma unroll
  for (int f = 0; f < 10; ++f) w1r[f] = evW1[f * 256 + u];
  float t0 = 0.f, t1 = 0.f, t2 = 0.f, t3 = 0.f, va = 0.f;
#pragma unroll 4
  for (int e = 0; e < n; ++e) {
    float ax = sexp[e][0], ay = sexp[e][1], az = sexp[e][2], aw = sexp[e][3];
    int j = scols[e];
    float h1 = evb;
#pragma unroll
    for (int f = 0; f < 10; ++f) h1 += sef[e][f] * w1r[f];
    float g1 = gelu_f(h1);
    t0 += ax * g1; t1 += ay * g1; t2 += az * g1; t3 += aw * g1;
    float ah = (h == 0) ? ax : (h == 1) ? ay : (h == 2) ? az : aw;
    va += ah * qkv[((size_t)(b * 256 + j)) * 768 + 512 + u];
  }
  size_t tbase = (size_t)r * 1024 + u;
  atomicAdd(&tb[tbase], t0);
  atomicAdd(&tb[tbase + 256], t1);
  atomicAdd(&tb[tbase + 512], t2);
  atomicAdd(&tb[tbase + 768], t3);
  atomicAdd(&vs[(size_t)r * 256 + u], va);
}

__global__ __launch_bounds__(256) void k_zero(float4* __restrict__ p) {
  p[(size_t)blockIdx.x * 256 + threadIdx.x] = make_float4(0.f, 0.f, 0.f, 0.f);
}

extern "C" void kernel_launch(void* const* d_in, const int* in_sizes, int n_in,
                              void* d_out, int out_size, void* d_ws, size_t ws_size,
                              hipStream_t stream) {
  (void)in_sizes; (void)n_in; (void)out_size; (void)ws_size;

  char* wp = (char*)d_ws;
  auto carve = [&](size_t bytes) -> char* {
    char* p = wp;
    wp += ((bytes + 255) / 256) * 256;
    return p;
  };
  int*   gctr   = (int*)carve(4);
  float* lsb    = (float*)carve(16);
  int*   valid  = (int*)carve(1024 * 4);
  int*   deg    = (int*)carve(1024 * 4);
  int*   rowptr = (int*)carve(1024 * 4);
  int*   colsb  = (int*)carve(MAXE * 4);
  int*   knn    = (int*)carve(1024 * 3 * 4);
  float* rowsum = (float*)carve(8192 * 4);
  float* blobF  = (float*)carve((size_t)(262144 + NONX) * 4);
  unsigned short* blobB = (unsigned short*)carve((size_t)BF16_TOTAL * 2);
  float* qkv    = (float*)carve((size_t)1024 * 768 * 4);
  float* xcur   = (float*)carve((size_t)262144 * 4);
  float* tb     = (float*)carve((size_t)1048576 * 4);   // t-accum; reused as FF hidden
  float* vs     = (float*)carve((size_t)262144 * 4);    // contiguous after tb
  unsigned short* oi = (unsigned short*)carve((size_t)262144 * 2);

  const float* Xf    = blobF + 0;
  const float* Cf    = blobF + 262144;
  const float* ebW1  = blobF + 264192;
  const float* ebB1  = blobF + 269824;
  const float* ebW2  = blobF + 270336;
  const float* ebB2  = blobF + 272384;
  const float* evW1  = blobF + 272448;
  const float* evB1  = blobF + 278080;
  const float* evB2  = blobF + 278592;
  const float* boB   = blobF + 279104;
  const float* ln1w  = blobF + 279616;
  const float* ln1b  = blobF + 280128;
  const float* ln2w  = blobF + 280640;
  const float* ln2b  = blobF + 281152;
  const float* ffb1  = blobF + 281664;
  const float* ffb2  = blobF + 283712;
  const unsigned short* WqB   = blobB + 0;
  const unsigned short* WoB   = blobB + 393216;
  const unsigned short* evW2B = blobB + 524288;
  const unsigned short* ffw1B = blobB + 655360;
  const unsigned short* ffw2B = blobB + 1179648;

  PtrPack pp;
  for (int i = 0; i < 23; ++i) pp.p[i] = d_in[i];
  const unsigned* probe = (const unsigned*)d_in[15];

  k_convert<<<2048, 256, 0, stream>>>(pp, blobF, blobB, valid, rowsum, tb, gctr);
  k_knn<<<256, 256, 0, stream>>>(Cf, valid, knn);
  k_csr<<<4, 256, 0, stream>>>(Cf, valid, knn, lsb, deg, rowptr, colsb, gctr);

  for (int l = 0; l < 2; ++l) {
    const float* xsrc = (l == 0) ? Xf : xcur;
    float* rsumL = rowsum + l * 4096;
    k_mfma_qkv<<<dim3(16, 12), 256, 0, stream>>>(xsrc, ln1w + l * 256, ln1b + l * 256,
                                                 WqB + l * 65536, qkv);
    k_edge<<<8192, 256, 0, stream>>>(Cf, qkv, rowptr, deg, colsb, lsb,
                                     ebW1 + l * 2816, ebB1 + l * 256,
                                     ebW2 + l * 1024, ebB2 + l * 4,
                                     evW1 + l * 2816, evB1 + l * 256,
                                     rsumL, tb, vs);
    // epi GEMM: oi = (vs + t~ @ evW2)/S + evB2, normalization fused (AMODE 4)
    k_mfma<4, 2><<<dim3(16, 4), 256, 0, stream>>>(tb, 1024, 1024, evW2B + l * 65536, 256,
                                                  evB2 + l * 256, vs, oi, 256, 256,
                                                  nullptr, nullptr, nullptr, rsumL);
    // Wo GEMM + residual
    k_mfma<0, 0><<<dim3(16, 4), 256, 0, stream>>>(oi, 256, 0, WoB + l * 65536, 256,
                                                  boB + l * 256, xsrc, xcur, 256, 256,
                                                  nullptr, nullptr, nullptr, nullptr);
    // FF1 with fused LN2
    k_mfma<3, 0><<<dim3(16, 16), 256, 0, stream>>>(xcur, 256, 0, ffw1B + l * 262144, 1024,
                                                   ffb1 + l * 1024, nullptr, tb, 1024, 256,
                                                   nullptr, ln2w + l * 256, ln2b + l * 256, nullptr);
    // FF2 gated + residual
    if (l == 0) {
      k_mfma<1, 0><<<dim3(16, 4), 256, 0, stream>>>(tb, 1024, 0, ffw2B + l * 131072, 256,
                                                    ffb2 + l * 256, xcur, xcur, 256, 512,
                                                    nullptr, nullptr, nullptr, nullptr);
      k_zero<<<1280, 256, 0, stream>>>((float4*)tb);   // re-zero tb+vs for layer 1
    } else {
      k_mfma<1, 1><<<dim3(16, 4), 256, 0, stream>>>(tb, 1024, 0, ffw2B + l * 131072, 256,
                                                    ffb2 + l * 256, xcur, d_out, 256, 512,
                                                    probe, nullptr, nullptr, nullptr);
    }
  }
}

// Round 9
// 397.715 us; speedup vs baseline: 1.0381x; 1.0381x over previous
//
#include <hip/hip_runtime.h>

// LocalGraphTransformerEncoder on MI355X (gfx950). Round 9.
// R8 post-mortem: absmax 1.2 from one of {bf16 ef staging, W1^T repack,
// k_g1 MFMA} — unlocalizable by inspection (k-layout unfalsifiable). R9 keeps
// the R8 architecture (edge MLP hoisted out of gather loops) but computes it
// with R6-proven fp32 math: k_mlp = thread per (edge, 16 channels), W1 in LDS,
// fp32 edge features recomputed in-kernel, G stored fp32. k_csr/k_convert
// reverted to R7-exact versions.

#define MAXE  16384
#define NONX  22080
#define BF16_TOTAL 1441792

typedef __attribute__((ext_vector_type(8))) short bf16x8;
typedef __attribute__((ext_vector_type(4))) float f32x4;

struct PtrPack { const void* p[23]; };

__device__ __forceinline__ float bf2f(unsigned short s) {
  return __uint_as_float(((unsigned)s) << 16);
}
__device__ __forceinline__ unsigned short f2bf(float f) {
  unsigned u = __float_as_uint(f);
  u += 0x7fffu + ((u >> 16) & 1u);
  return (unsigned short)(u >> 16);
}
__device__ __forceinline__ float gelu_f(float x) {
  return 0.5f * x * (1.0f + erff(x * 0.70710678118654752440f));
}
__device__ __forceinline__ float wave_red_sum(float v) {
#pragma unroll
  for (int o = 32; o > 0; o >>= 1) v += __shfl_xor(v, o);
  return v;
}

__device__ __forceinline__ void edge_feats(int i, int j, float cxi, float cyi,
                                           float cxj, float cyj, float lsd, float* e) {
  float dx = cxj - cxi, dy = cyj - cyi;
  float dist = sqrtf(dx * dx + dy * dy + 1e-8f);
  e[0] = dx; e[1] = dy; e[2] = dist; e[3] = dist / lsd;
  bool qic = (i == 0), kic = (j == 0), eye = (i == j);
  e[4] = qic ? 1.f : 0.f;
  e[5] = kic ? 1.f : 0.f;
  e[6] = eye ? 1.f : 0.f;
  e[7] = (!qic && !kic && !eye) ? 1.f : 0.f;
  int hi = (i == 0) ? 0 : ((i < 128) ? 1 : 2);
  int hj = (j == 0) ? 0 : ((j < 128) ? 1 : 2);
  e[8] = (hi == hj) ? 1.f : 0.f;
  int hd = hj - hi;
  e[9] = (float)(hd < 0 ? -hd : hd);
}

// ---------- convert: fp32 smalls + bf16 weights + valid + zero rowsum/tb/vs ----------
__global__ __launch_bounds__(256) void k_convert(PtrPack pp, float* __restrict__ blobF,
                                                 unsigned short* __restrict__ blobB,
                                                 int* __restrict__ valid,
                                                 float* __restrict__ rowsum,
                                                 float* __restrict__ tbvs,
                                                 int* __restrict__ gctr) {
  bool isf32 = (*(const unsigned*)pp.p[15] == 0x3F800000u);
  int t = threadIdx.x;
  if (blockIdx.x == 0 && t == 0) *gctr = 0;
  if (blockIdx.x < 1024) {
    if (blockIdx.x < 32) rowsum[blockIdx.x * 256 + t] = 0.f;
    int r = blockIdx.x;
    int idx = r * 256 + t;
    float v = isf32 ? ((const float*)pp.p[0])[idx]
                    : bf2f(((const unsigned short*)pp.p[0])[idx]);
    blobF[idx] = v;
    __shared__ float s[4];
    float a = wave_red_sum(fabsf(v));
    if ((t & 63) == 0) s[t >> 6] = a;
    __syncthreads();
    if (t == 0) valid[r] = ((s[0] + s[1] + s[2] + s[3]) > 0.0f) || ((r & 255) == 0);
  } else {
    for (int z = (blockIdx.x - 1024) * 256 + t; z < 1310720; z += 262144)
      tbvs[z] = 0.f;
    const int fst[16] = {0,2048,7680,8192,10240,10304,15936,16448,16960,17472,17984,18496,19008,19520,21568,22080};
    const int fsz[15] = {2048,5632,512,2048,8,5632,512,512,512,512,512,512,512,2048,512};
    const int fin[15] = {1,5,6,7,8,9,10,12,14,15,16,17,18,20,22};
    const int bst[8]  = {0,131072,262144,393216,524288,655360,1179648,1441792};
    const int bin[7]  = {2,3,4,13,11,19,21};
    for (int idx = (blockIdx.x - 1024) * 256 + t; idx < NONX + BF16_TOTAL; idx += 1024 * 256) {
      if (idx < NONX) {
        int s = 0;
        while (s < 14 && idx >= fst[s + 1]) ++s;
        int e = idx - fst[s];
        float v = 0.f;
        if (e < fsz[s]) v = isf32 ? ((const float*)pp.p[fin[s]])[e]
                                  : bf2f(((const unsigned short*)pp.p[fin[s]])[e]);
        blobF[262144 + idx] = v;
      } else {
        int bi = idx - NONX;
        int s = 0;
        while (s < 6 && bi >= bst[s + 1]) ++s;
        int e = bi - bst[s];
        blobB[bi] = isf32 ? f2bf(((const float*)pp.p[bin[s]])[e])
                          : ((const unsigned short*)pp.p[bin[s]])[e];
      }
    }
  }
}

// ---------- kNN ----------
__global__ __launch_bounds__(256) void k_knn(const float* __restrict__ cf,
                                             const int* __restrict__ valid,
                                             int* __restrict__ knn) {
  int blk = blockIdx.x;
  int b = blk >> 6;
  int w = threadIdx.x >> 6, lane = threadIdx.x & 63;
  int i = (blk & 63) * 4 + w;
  const float2* cc = (const float2*)(cf + b * 512);
  float2 ci = cc[i];
  bool vi = (valid[b * 256 + i] != 0) && (i != 0);
  unsigned long long key[4];
#pragma unroll
  for (int k = 0; k < 4; ++k) {
    int j = lane + 64 * k;
    bool ok = vi && (j != 0) && (j != i) && (valid[b * 256 + j] != 0);
    unsigned long long kk = ~0ull;
    if (ok) {
      float2 cj = cc[j];
      float dx = ci.x - cj.x, dy = ci.y - cj.y;
      float dd = sqrtf(dx * dx + dy * dy);
      kk = (((unsigned long long)__float_as_uint(dd)) << 32) | (unsigned)j;
    }
    key[k] = kk;
  }
  int out[3];
#pragma unroll
  for (int rnd = 0; rnd < 3; ++rnd) {
    unsigned long long m = key[0];
    if (key[1] < m) m = key[1];
    if (key[2] < m) m = key[2];
    if (key[3] < m) m = key[3];
#pragma unroll
    for (int o = 32; o > 0; o >>= 1) {
      unsigned long long om = __shfl_xor(m, o);
      if (om < m) m = om;
    }
    out[rnd] = (m != ~0ull) ? (int)(m & 0xFFFFFFFFull) : -1;
#pragma unroll
    for (int k = 0; k < 4; ++k)
      if (key[k] == m) key[k] = ~0ull;
  }
  if (lane == 0) {
    knn[(b * 256 + i) * 3 + 0] = out[0];
    knn[(b * 256 + i) * 3 + 1] = out[1];
    knn[(b * 256 + i) * 3 + 2] = out[2];
  }
}

// ---------- CSR build (R7-exact) ----------
__global__ __launch_bounds__(256) void k_csr(const float* __restrict__ cf,
                                             const int* __restrict__ valid,
                                             const int* __restrict__ knn,
                                             float* __restrict__ lsbuf,
                                             int* __restrict__ deg, int* __restrict__ rowptr,
                                             int* __restrict__ rowof, int* __restrict__ colsb,
                                             int* __restrict__ gctr) {
  int b = blockIdx.x, t = threadIdx.x;
  __shared__ unsigned adjw[256][8];
  __shared__ float sred[8];
  __shared__ int wsum[4];
  __shared__ int sbase;

  int r = b * 256 + t;
  float cx = cf[r * 2 + 0], cy = cf[r * 2 + 1];
  int lv = valid[r];
#pragma unroll
  for (int w = 0; w < 8; ++w) adjw[t][w] = 0u;
  __syncthreads();

  atomicOr(&adjw[t][t >> 5], 1u << (t & 31));
  if (t >= 1 && lv) {
    atomicOr(&adjw[0][t >> 5], 1u << (t & 31));
    atomicOr(&adjw[t][0], 1u);
  }
#pragma unroll
  for (int s = 0; s < 3; ++s) {
    int j = knn[r * 3 + s];
    if (j >= 0) {
      atomicOr(&adjw[t][j >> 5], 1u << (j & 31));
      atomicOr(&adjw[j][t >> 5], 1u << (t & 31));
    }
  }
  float cdist = sqrtf(cx * cx + cy * cy + 1e-8f);
  int nvm = (t >= 1) && lv;
  float rs = wave_red_sum(nvm ? cdist : 0.0f);
  float rc = wave_red_sum(nvm ? 1.0f : 0.0f);
  if ((t & 63) == 0) { sred[t >> 6] = rs; sred[4 + (t >> 6)] = rc; }
  __syncthreads();

  if (t == 0) {
    float totd = sred[0] + sred[1] + sred[2] + sred[3];
    float totc = sred[4] + sred[5] + sred[6] + sred[7];
    float ls = totd / fmaxf(totc, 1.0f);
    ls = (ls > 0.0f) ? ls : 1.0f;
    lsbuf[b] = fmaxf(ls, 1e-6f);
  }

  int dg = 0;
#pragma unroll
  for (int w = 0; w < 8; ++w) dg += __popc(adjw[t][w]);

  int lane = t & 63, wv = t >> 6;
  int x = dg;
#pragma unroll
  for (int off = 1; off < 64; off <<= 1) {
    int y = __shfl_up(x, off);
    if (lane >= off) x += y;
  }
  if (lane == 63) wsum[wv] = x;
  __syncthreads();
  if (t == 0) sbase = atomicAdd(gctr, wsum[0] + wsum[1] + wsum[2] + wsum[3]);
  __syncthreads();
  int woff = 0;
#pragma unroll
  for (int k2 = 0; k2 < 4; ++k2) woff += (k2 < wv) ? wsum[k2] : 0;
  int off0 = sbase + woff + x - dg;

  rowptr[r] = off0;
  deg[r] = dg;
  int o = off0;
#pragma unroll
  for (int w = 0; w < 8; ++w) {
    unsigned bits = adjw[t][w];
    while (bits) {
      int bp = __ffs(bits) - 1;
      colsb[o] = w * 32 + bp;
      rowof[o] = r;
      ++o;
      bits &= bits - 1;
    }
  }
}

// ---------- k_mlp: G = gelu(ef @ W1 + b1), fp32 VALU, thread=(edge,16ch) ----------
__global__ __launch_bounds__(256) void k_mlp(const float* __restrict__ cf,
                                             const int* __restrict__ rowof,
                                             const int* __restrict__ colsb,
                                             const int* __restrict__ gctr,
                                             const float* __restrict__ lsbuf,
                                             const float* __restrict__ ebW1,
                                             const float* __restrict__ ebB1,
                                             const float* __restrict__ evW1,
                                             const float* __restrict__ evB1,
                                             float* __restrict__ Geb,
                                             float* __restrict__ Gev) {
  int E = *gctr;
  int e0 = blockIdx.x * 16;
  if (e0 >= E) return;
  int sel = blockIdx.y;
  const float* W1 = sel ? evW1 : ebW1;
  const float* B1 = sel ? evB1 : ebB1;
  float* G = sel ? Gev : Geb;
  __shared__ float sW[256][12];   // [channel][feature 0..9, pad, bias]
  int t = threadIdx.x;
#pragma unroll
  for (int f = 0; f < 10; ++f) sW[t][f] = W1[f * 256 + t];
  sW[t][11] = B1[t];
  __syncthreads();
  int el = t >> 4, cg = t & 15;
  int ge = e0 + el;
  if (ge >= E) return;
  int r = rowof[ge], j = colsb[ge];
  int b = r >> 8, i = r & 255;
  const float2* cc = (const float2*)cf;
  float2 ci = cc[b * 256 + i], cj = cc[b * 256 + j];
  float ef[10];
  edge_feats(i, j, ci.x, ci.y, cj.x, cj.y, lsbuf[b], ef);
  float out[16];
#pragma unroll
  for (int k = 0; k < 16; ++k) {
    int c = cg * 16 + k;
    float h1 = sW[c][11];
#pragma unroll
    for (int f = 0; f < 10; ++f) h1 += ef[f] * sW[c][f];
    out[k] = gelu_f(h1);
  }
#pragma unroll
  for (int k = 0; k < 16; k += 4)
    *(float4*)&G[(size_t)ge * 256 + cg * 16 + k] =
        make_float4(out[k], out[k + 1], out[k + 2], out[k + 3]);
}

// ---------- k_sim: wave per edge; qk dots + G_eb @ W2; exp -> esim ----------
__global__ __launch_bounds__(256) void k_sim(const float* __restrict__ qkv,
                                             const int* __restrict__ rowof,
                                             const int* __restrict__ colsb,
                                             const int* __restrict__ gctr,
                                             const float* __restrict__ Geb,
                                             const float* __restrict__ ebW2,
                                             const float* __restrict__ ebB2,
                                             float* __restrict__ esim) {
  int E = *gctr;
  int lane = threadIdx.x & 63, w = threadIdx.x >> 6;
  float W2r[4][4];
#pragma unroll
  for (int kk = 0; kk < 4; ++kk) {
    float4 w2 = *(const float4*)(ebW2 + (kk * 64 + lane) * 4);
    W2r[kk][0] = w2.x; W2r[kk][1] = w2.y; W2r[kk][2] = w2.z; W2r[kk][3] = w2.w;
  }
  float b20 = ebB2[0], b21 = ebB2[1], b22 = ebB2[2], b23 = ebB2[3];
  for (int g = blockIdx.x * 4 + w; g < E; g += 4096) {
    int r = rowof[g], j = colsb[g];
    int b = r >> 8;
    float red[8];
#pragma unroll
    for (int z = 0; z < 8; ++z) red[z] = 0.0f;
#pragma unroll
    for (int kk = 0; kk < 4; ++kk) {
      int c = kk * 64 + lane;
      float g1 = Geb[(size_t)g * 256 + c];
      red[4] += g1 * W2r[kk][0];
      red[5] += g1 * W2r[kk][1];
      red[6] += g1 * W2r[kk][2];
      red[7] += g1 * W2r[kk][3];
      red[kk] = qkv[(size_t)r * 768 + c] * qkv[((size_t)(b * 256 + j)) * 768 + 256 + c];
    }
#pragma unroll
    for (int z = 0; z < 8; ++z) {
#pragma unroll
      for (int o = 32; o > 0; o >>= 1) red[z] += __shfl_xor(red[z], o);
    }
    if (lane == 0) {
      float4 o4;
      o4.x = expf(red[0] * 0.125f + red[4] + b20);
      o4.y = expf(red[1] * 0.125f + red[5] + b21);
      o4.z = expf(red[2] * 0.125f + red[6] + b22);
      o4.w = expf(red[3] * 0.125f + red[7] + b23);
      *(float4*)&esim[(size_t)g * 4] = o4;
    }
  }
}

// ---------- k_accum: block/(row,32-chunk); chunk rowsum atomics; unnormalized t~/v~ ----------
__global__ __launch_bounds__(256, 4) void k_accum(const float* __restrict__ qkv,
                                                  const int* __restrict__ rowptr,
                                                  const int* __restrict__ deg,
                                                  const int* __restrict__ colsb,
                                                  const float* __restrict__ esim,
                                                  const float* __restrict__ Gev,
                                                  float* __restrict__ rowsum,
                                                  float* __restrict__ tb,
                                                  float* __restrict__ vs) {
  int rc = blockIdx.x;
  int r = rc >> 3, ch = rc & 7;
  int d = deg[r];
  int e0 = ch * 32;
  if (e0 >= d) return;
  int n = min(32, d - e0);
  int base = rowptr[r] + e0;
  int b = r >> 8;
  int u = threadIdx.x, h = u >> 6;

  __shared__ int scols[32];
  __shared__ float4 sattn[32];
  if (u < n) {
    scols[u] = colsb[base + u];
    sattn[u] = *(const float4*)&esim[(size_t)(base + u) * 4];
  }
  __syncthreads();

  if (u < 4) {
    float s = 0.f;
    for (int e = 0; e < n; ++e)
      s += (u == 0) ? sattn[e].x : (u == 1) ? sattn[e].y : (u == 2) ? sattn[e].z : sattn[e].w;
    atomicAdd(&rowsum[r * 4 + u], s);
  }

  float t0 = 0.f, t1 = 0.f, t2 = 0.f, t3 = 0.f, va = 0.f;
#pragma unroll 4
  for (int e = 0; e < n; ++e) {
    float4 a = sattn[e];
    int j = scols[e];
    float g1 = Gev[(size_t)(base + e) * 256 + u];
    t0 += a.x * g1; t1 += a.y * g1; t2 += a.z * g1; t3 += a.w * g1;
    float ah = (h == 0) ? a.x : (h == 1) ? a.y : (h == 2) ? a.z : a.w;
    va += ah * qkv[((size_t)(b * 256 + j)) * 768 + 512 + u];
  }
  size_t tbase = (size_t)r * 1024 + u;
  atomicAdd(&tb[tbase], t0);
  atomicAdd(&tb[tbase + 256], t1);
  atomicAdd(&tb[tbase + 512], t2);
  atomicAdd(&tb[tbase + 768], t3);
  atomicAdd(&vs[(size_t)r * 256 + u], va);
}

// ---------- bf16 MFMA GEMM body (R7-proven) ----------
// AMODE: 0=bf16 A | 1=gated fp32 (gate +512, lda=1024) | 3=LN-fused fp32
//        4=fp32 scaled by 1/rowsum[row*4+rsh] (resid scaled too)
// OMODE: 0=fp32 | 1=probe bf16/fp32 | 2=bf16
template <int AMODE, int OMODE>
__device__ __forceinline__ void mfma_body(const void* Aptr, int lda,
                                          const unsigned short* __restrict__ B, int ldb, int n0B,
                                          const float* __restrict__ bias,
                                          const float* resid,
                                          void* C, int ldc, int n0C,
                                          int m0, int K, bool obf,
                                          const float* __restrict__ lnG,
                                          const float* __restrict__ lnB,
                                          const float* __restrict__ rs4, int rsh) {
  __shared__ short As[64][40];
  __shared__ short Bs[64][40];
  __shared__ float sG[256], sB2[256], sMean[64], sRstd[64];
  __shared__ float sSc[64];
  int t = threadIdx.x, lane = t & 63, w = t >> 6;

  if (AMODE == 3) {
    sG[t] = lnG[t]; sB2[t] = lnB[t];
    int row = t >> 2, qq = t & 3;
    const float* xr = (const float*)Aptr + (size_t)(m0 + row) * lda + qq * 64;
    float s = 0.f, ss = 0.f;
#pragma unroll
    for (int ii = 0; ii < 16; ++ii) {
      float4 v4 = *(const float4*)(xr + ii * 4);
      s += v4.x + v4.y + v4.z + v4.w;
      ss += v4.x * v4.x + v4.y * v4.y + v4.z * v4.z + v4.w * v4.w;
    }
    s += __shfl_xor(s, 1); s += __shfl_xor(s, 2);
    ss += __shfl_xor(ss, 1); ss += __shfl_xor(ss, 2);
    if (qq == 0) {
      float m = s * (1.f / 256.f);
      float var = ss * (1.f / 256.f) - m * m;
      sMean[row] = m;
      sRstd[row] = 1.f / sqrtf(var + 1e-5f);
    }
    __syncthreads();
  }
  if (AMODE == 4) {
    if (t < 64) sSc[t] = 1.0f / rs4[(m0 + t) * 4 + rsh];
    __syncthreads();
  }

  f32x4 acc[4];
#pragma unroll
  for (int nt = 0; nt < 4; ++nt)
#pragma unroll
    for (int e = 0; e < 4; ++e) acc[nt][e] = 0.0f;

  int am = t >> 2, ak = (t & 3) * 8;
  int bk = t >> 3, bn = (t & 7) * 8;

  for (int k0 = 0; k0 < K; k0 += 32) {
    if (AMODE == 0) {
      const unsigned short* ap = (const unsigned short*)Aptr + (size_t)(m0 + am) * lda + k0 + ak;
      *(bf16x8*)&As[am][ak] = *(const bf16x8*)ap;
    } else if (AMODE == 1) {
      const float* ap = (const float*)Aptr + (size_t)(m0 + am) * lda + k0 + ak;
      float4 a0 = *(const float4*)ap;
      float4 a1 = *(const float4*)(ap + 4);
      float4 g0 = *(const float4*)(ap + 512);
      float4 g1 = *(const float4*)(ap + 516);
      short tmp[8];
      tmp[0] = (short)f2bf(a0.x * gelu_f(g0.x));
      tmp[1] = (short)f2bf(a0.y * gelu_f(g0.y));
      tmp[2] = (short)f2bf(a0.z * gelu_f(g0.z));
      tmp[3] = (short)f2bf(a0.w * gelu_f(g0.w));
      tmp[4] = (short)f2bf(a1.x * gelu_f(g1.x));
      tmp[5] = (short)f2bf(a1.y * gelu_f(g1.y));
      tmp[6] = (short)f2bf(a1.z * gelu_f(g1.z));
      tmp[7] = (short)f2bf(a1.w * gelu_f(g1.w));
      *(bf16x8*)&As[am][ak] = *(bf16x8*)tmp;
    } else if (AMODE == 4) {
      const float* ap = (const float*)Aptr + (size_t)(m0 + am) * lda + k0 + ak;
      float4 a0 = *(const float4*)ap;
      float4 a1 = *(const float4*)(ap + 4);
      float sc = sSc[am];
      short tmp[8];
      tmp[0] = (short)f2bf(a0.x * sc); tmp[1] = (short)f2bf(a0.y * sc);
      tmp[2] = (short)f2bf(a0.z * sc); tmp[3] = (short)f2bf(a0.w * sc);
      tmp[4] = (short)f2bf(a1.x * sc); tmp[5] = (short)f2bf(a1.y * sc);
      tmp[6] = (short)f2bf(a1.z * sc); tmp[7] = (short)f2bf(a1.w * sc);
      *(bf16x8*)&As[am][ak] = *(bf16x8*)tmp;
    } else {
      const float* ap = (const float*)Aptr + (size_t)(m0 + am) * lda + k0 + ak;
      float4 a0 = *(const float4*)ap;
      float4 a1 = *(const float4*)(ap + 4);
      float mm = sMean[am], rr = sRstd[am];
      short tmp[8];
      int kb = k0 + ak;
      tmp[0] = (short)f2bf((a0.x - mm) * rr * sG[kb + 0] + sB2[kb + 0]);
      tmp[1] = (short)f2bf((a0.y - mm) * rr * sG[kb + 1] + sB2[kb + 1]);
      tmp[2] = (short)f2bf((a0.z - mm) * rr * sG[kb + 2] + sB2[kb + 2]);
      tmp[3] = (short)f2bf((a0.w - mm) * rr * sG[kb + 3] + sB2[kb + 3]);
      tmp[4] = (short)f2bf((a1.x - mm) * rr * sG[kb + 4] + sB2[kb + 4]);
      tmp[5] = (short)f2bf((a1.y - mm) * rr * sG[kb + 5] + sB2[kb + 5]);
      tmp[6] = (short)f2bf((a1.z - mm) * rr * sG[kb + 6] + sB2[kb + 6]);
      tmp[7] = (short)f2bf((a1.w - mm) * rr * sG[kb + 7] + sB2[kb + 7]);
      *(bf16x8*)&As[am][ak] = *(bf16x8*)tmp;
    }
    {
      const unsigned short* bp = B + (size_t)(k0 + bk) * ldb + n0B + bn;
      bf16x8 bv = *(const bf16x8*)bp;
      Bs[bn + 0][bk] = bv[0]; Bs[bn + 1][bk] = bv[1];
      Bs[bn + 2][bk] = bv[2]; Bs[bn + 3][bk] = bv[3];
      Bs[bn + 4][bk] = bv[4]; Bs[bn + 5][bk] = bv[5];
      Bs[bn + 6][bk] = bv[6]; Bs[bn + 7][bk] = bv[7];
    }
    __syncthreads();
    int q = lane >> 4;
    bf16x8 af = *(const bf16x8*)&As[w * 16 + (lane & 15)][q * 8];
#pragma unroll
    for (int nt = 0; nt < 4; ++nt) {
      bf16x8 bf = *(const bf16x8*)&Bs[nt * 16 + (lane & 15)][q * 8];
      acc[nt] = __builtin_amdgcn_mfma_f32_16x16x32_bf16(af, bf, acc[nt], 0, 0, 0);
    }
    __syncthreads();
  }

  int q = lane >> 4;
#pragma unroll
  for (int nt = 0; nt < 4; ++nt) {
    int col = n0C + nt * 16 + (lane & 15);
    float bv = bias ? bias[n0B + nt * 16 + (lane & 15)] : 0.0f;
#pragma unroll
    for (int rr = 0; rr < 4; ++rr) {
      int row = m0 + w * 16 + q * 4 + rr;
      float v = acc[nt][rr] + bv;
      if (resid) {
        float rv = resid[(size_t)row * ldc + col];
        v += (AMODE == 4) ? rv * sSc[row - m0] : rv;
      }
      if (OMODE == 2 || (OMODE == 1 && obf)) {
        ((unsigned short*)C)[(size_t)row * ldc + col] = f2bf(v);
      } else {
        ((float*)C)[(size_t)row * ldc + col] = v;
      }
    }
  }
}

template <int AMODE, int OMODE>
__global__ __launch_bounds__(256) void k_mfma(const void* A, int lda, int aYoffBytes,
                                              const unsigned short* B, int ldb,
                                              const float* bias, const float* resid,
                                              void* C, int ldc, int K,
                                              const unsigned* probe,
                                              const float* lnG, const float* lnB,
                                              const float* rs4) {
  bool obf = (OMODE == 1) && probe && (*probe != 0x3F800000u);
  int n0 = blockIdx.y * 64;
  const void* Ap = (const char*)A + (size_t)aYoffBytes * blockIdx.y;
  mfma_body<AMODE, OMODE>(Ap, lda, B, ldb, n0, bias, resid, C, ldc, n0,
                          blockIdx.x * 64, K, obf, lnG, lnB, rs4, blockIdx.y);
}

__global__ __launch_bounds__(256) void k_mfma_qkv(const float* X,
                                                  const float* lnG, const float* lnB,
                                                  const unsigned short* WqL, float* qkv) {
  int sel = blockIdx.y >> 2;
  const unsigned short* B = WqL + sel * 131072;
  int n0B = (blockIdx.y & 3) * 64;
  int n0C = blockIdx.y * 64;
  mfma_body<3, 0>(X, 256, B, 256, n0B, nullptr, nullptr, qkv, 768, n0C,
                  blockIdx.x * 64, 256, false, lnG, lnB, nullptr, 0);
}

__global__ __launch_bounds__(256) void k_zero(float4* __restrict__ p) {
  p[(size_t)blockIdx.x * 256 + threadIdx.x] = make_float4(0.f, 0.f, 0.f, 0.f);
}

extern "C" void kernel_launch(void* const* d_in, const int* in_sizes, int n_in,
                              void* d_out, int out_size, void* d_ws, size_t ws_size,
                              hipStream_t stream) {
  (void)in_sizes; (void)n_in; (void)out_size; (void)ws_size;

  char* wp = (char*)d_ws;
  auto carve = [&](size_t bytes) -> char* {
    char* p = wp;
    wp += ((bytes + 255) / 256) * 256;
    return p;
  };
  int*   gctr   = (int*)carve(4);
  float* lsb    = (float*)carve(16);
  int*   valid  = (int*)carve(1024 * 4);
  int*   deg    = (int*)carve(1024 * 4);
  int*   rowptr = (int*)carve(1024 * 4);
  int*   rowof  = (int*)carve(MAXE * 4);
  int*   colsb  = (int*)carve(MAXE * 4);
  int*   knn    = (int*)carve(1024 * 3 * 4);
  float* rowsum = (float*)carve(8192 * 4);
  float* esim   = (float*)carve((size_t)MAXE * 16);
  float* Geb    = (float*)carve((size_t)MAXE * 256 * 4);
  float* Gev    = (float*)carve((size_t)MAXE * 256 * 4);
  float* blobF  = (float*)carve((size_t)(262144 + NONX) * 4);
  unsigned short* blobB = (unsigned short*)carve((size_t)BF16_TOTAL * 2);
  float* qkv    = (float*)carve((size_t)1024 * 768 * 4);
  float* xcur   = (float*)carve((size_t)262144 * 4);
  float* tb     = (float*)carve((size_t)1048576 * 4);   // t-accum; reused as FF hidden
  float* vs     = (float*)carve((size_t)262144 * 4);    // contiguous after tb
  unsigned short* oi = (unsigned short*)carve((size_t)262144 * 2);

  const float* Xf    = blobF + 0;
  const float* Cf    = blobF + 262144;
  const float* ebW1  = blobF + 264192;
  const float* ebB1  = blobF + 269824;
  const float* ebW2  = blobF + 270336;
  const float* ebB2  = blobF + 272384;
  const float* evW1  = blobF + 272448;
  const float* evB1  = blobF + 278080;
  const float* evB2  = blobF + 278592;
  const float* boB   = blobF + 279104;
  const float* ln1w  = blobF + 279616;
  const float* ln1b  = blobF + 280128;
  const float* ln2w  = blobF + 280640;
  const float* ln2b  = blobF + 281152;
  const float* ffb1  = blobF + 281664;
  const float* ffb2  = blobF + 283712;
  const unsigned short* WqB   = blobB + 0;
  const unsigned short* WoB   = blobB + 393216;
  const unsigned short* evW2B = blobB + 524288;
  const unsigned short* ffw1B = blobB + 655360;
  const unsigned short* ffw2B = blobB + 1179648;

  PtrPack pp;
  for (int i = 0; i < 23; ++i) pp.p[i] = d_in[i];
  const unsigned* probe = (const unsigned*)d_in[15];

  k_convert<<<2048, 256, 0, stream>>>(pp, blobF, blobB, valid, rowsum, tb, gctr);
  k_knn<<<256, 256, 0, stream>>>(Cf, valid, knn);
  k_csr<<<4, 256, 0, stream>>>(Cf, valid, knn, lsb, deg, rowptr, rowof, colsb, gctr);

  for (int l = 0; l < 2; ++l) {
    const float* xsrc = (l == 0) ? Xf : xcur;
    float* rsumL = rowsum + l * 4096;
    k_mfma_qkv<<<dim3(16, 12), 256, 0, stream>>>(xsrc, ln1w + l * 256, ln1b + l * 256,
                                                 WqB + l * 65536, qkv);
    k_mlp<<<dim3(1024, 2), 256, 0, stream>>>(Cf, rowof, colsb, gctr, lsb,
                                             ebW1 + l * 2816, ebB1 + l * 256,
                                             evW1 + l * 2816, evB1 + l * 256, Geb, Gev);
    k_sim<<<1024, 256, 0, stream>>>(qkv, rowof, colsb, gctr, Geb,
                                    ebW2 + l * 1024, ebB2 + l * 4, esim);
    k_accum<<<8192, 256, 0, stream>>>(qkv, rowptr, deg, colsb, esim, Gev,
                                      rsumL, tb, vs);
    // epi GEMM: oi = (vs~ + t~ @ evW2)/S + evB2 (AMODE 4 normalizes)
    k_mfma<4, 2><<<dim3(16, 4), 256, 0, stream>>>(tb, 1024, 1024, evW2B + l * 65536, 256,
                                                  evB2 + l * 256, vs, oi, 256, 256,
                                                  nullptr, nullptr, nullptr, rsumL);
    // Wo GEMM + residual
    k_mfma<0, 0><<<dim3(16, 4), 256, 0, stream>>>(oi, 256, 0, WoB + l * 65536, 256,
                                                  boB + l * 256, xsrc, xcur, 256, 256,
                                                  nullptr, nullptr, nullptr, nullptr);
    // FF1 with fused LN2
    k_mfma<3, 0><<<dim3(16, 16), 256, 0, stream>>>(xcur, 256, 0, ffw1B + l * 262144, 1024,
                                                   ffb1 + l * 1024, nullptr, tb, 1024, 256,
                                                   nullptr, ln2w + l * 256, ln2b + l * 256, nullptr);
    // FF2 gated + residual
    if (l == 0) {
      k_mfma<1, 0><<<dim3(16, 4), 256, 0, stream>>>(tb, 1024, 0, ffw2B + l * 131072, 256,
                                                    ffb2 + l * 256, xcur, xcur, 256, 512,
                                                    nullptr, nullptr, nullptr, nullptr);
      k_zero<<<1280, 256, 0, stream>>>((float4*)tb);   // re-zero tb+vs for layer 1
    } else {
      k_mfma<1, 1><<<dim3(16, 4), 256, 0, stream>>>(tb, 1024, 0, ffw2B + l * 131072, 256,
                                                    ffb2 + l * 256, xcur, d_out, 256, 512,
                                                    probe, nullptr, nullptr, nullptr);
    }
  }
}